// Round 15
// baseline (526.689 us; speedup 1.0000x reference)
//
#include <hip/hip_runtime.h>
#include <hip/hip_cooperative_groups.h>
#include <cstddef>

namespace cg = cooperative_groups;

#define EPSF 1e-12f

constexpr int Bc = 16, Dc = 128, Lc = 4096, Kc = 4096;
constexpr int Nc = Bc * Lc;     // 65536
constexpr float TAU = 1e-4f;    // 2x split-bf16 err (~4e-5) + 8-bit pack err (~6e-5)
constexpr int RCAP = 32768;

typedef __attribute__((ext_vector_type(8))) short short8;
typedef __attribute__((ext_vector_type(4))) float f32x4;

__device__ __forceinline__ unsigned short f2bf(float f) {
    unsigned u = __float_as_uint(f);
    return (unsigned short)((u + 0x7fffu + ((u >> 16) & 1u)) >> 16);
}
__device__ __forceinline__ float bf2f(unsigned short u) {
    return __uint_as_float(((unsigned)u) << 16);
}

// ---------------------------------------------------------------------------
// Fully-fused cooperative kernel: 256 blocks x 512 threads (argmax's proven
// shape, 1 block/CU, co-resident). Three phases separated by grid.sync():
//   P1 prep:   normalize codebook -> cbn + pack MFMA blob (16 codes/block).
//   P2 argmax: exact r9/r14 body (best measured 177.8 us, MfmaUtil 53.5%).
//   P3 repair: r14's coalesced wave-per-code-pair re-argmax (grid-stride).
// Eliminates 2 kernel boundaries (~50 us of launch gap measured r11/r12).
// All per-phase numerics byte-identical to the r14-passing kernels.
// __threadfence() before each sync: cross-XCD visibility (Guideline 16).
// ---------------------------------------------------------------------------
__global__ __launch_bounds__(512, 2)
void k_fused(const float* __restrict__ emb, const float* __restrict__ x,
             float* __restrict__ cbn, char* __restrict__ blob,
             float* __restrict__ invn, float* __restrict__ out,
             float* __restrict__ lacc, int* __restrict__ rcnt,
             int* __restrict__ rlist) {
    cg::grid_group grid = cg::this_grid();
    __shared__ __align__(16) char smem[33280];

    const int tid  = threadIdx.x;
    const int w    = tid >> 6;
    const int lane = tid & 63;

    // ================= Phase 1: codebook prep =================
    {
        float (*cls)[128] = (float(*)[128])smem;   // [16][128] = 8192 B
        if (blockIdx.x == 0 && tid == 0) { *lacc = 0.f; *rcnt = 0; }
        #pragma unroll
        for (int c = 0; c < 2; ++c) {              // wave handles 2 codes
            int k = (blockIdx.x << 4) + (w << 1) + c;
            float2 v = ((const float2*)(emb + (size_t)k * Dc))[lane];
            float s = v.x * v.x + v.y * v.y;
            #pragma unroll
            for (int off = 32; off > 0; off >>= 1) s += __shfl_down(s, off);
            s = __shfl(s, 0);
            float inv = 1.f / fmaxf(sqrtf(s), EPSF);
            v.x *= inv; v.y *= inv;
            ((float2*)(cbn + (size_t)k * Dc))[lane] = v;
            cls[(w << 1) + c][lane * 2]     = v.x;
            cls[(w << 1) + c][lane * 2 + 1] = v.y;
        }
        __syncthreads();
        if (tid < 256) {       // 16 codes x 16 chunks
            int kl = tid >> 4, c = tid & 15;
            int kk = (blockIdx.x << 4) + kl;
            int kd = c >> 2, q = c & 3;
            short8 hh, ll;
            #pragma unroll
            for (int j = 0; j < 8; ++j) {
                float f = cls[kl][c * 8 + j];
                unsigned short hb = f2bf(f);
                hh[j] = (short)hb;
                ll[j] = (short)f2bf(f - bf2f(hb));
            }
            size_t base = (size_t)(kk >> 4) * 8192 + (size_t)(q * 16 + (kk & 15)) * 16;
            *(short8*)(blob + base + (kd * 2 + 0) * 1024) = hh;
            *(short8*)(blob + base + (kd * 2 + 1) * 1024) = ll;
        }
    }
    __threadfence();
    grid.sync();

    // ================= Phase 2: MFMA argmax (r9 body, verbatim) =========
    {
        float* xt   = (float*)smem;              // [64][129] (preamble overlay)
        float* invl = (float*)(smem + 33024);    // [64]
        const int m16  = lane & 15;
        const int quad = lane >> 4;
        const int rs   = w >> 1;      // rowset 0..3 (64 rows each)
        const int cs   = w & 1;       // codeset 0/1 (16 codes per tile)
        const int n0   = blockIdx.x * 256;
        const int bI   = n0 >> 12;
        const int l0   = n0 & (Lc - 1);
        const float* xb = x + (size_t)bI * Dc * Lc;

        // ---- preamble: 4 halves of 64 rows ----
        short8 ah[4][4], al[4][4];
        for (int h = 0; h < 4; ++h) {
            __syncthreads();
            #pragma unroll
            for (int j = 0; j < 4; ++j) {
                int fl = tid + j * 512;              // 0..2047
                int d = fl >> 4, lq = fl & 15;
                float4 v = *(const float4*)(xb + (size_t)d * Lc + l0 + h * 64 + lq * 4);
                xt[(lq * 4 + 0) * 129 + d] = v.x;
                xt[(lq * 4 + 1) * 129 + d] = v.y;
                xt[(lq * 4 + 2) * 129 + d] = v.z;
                xt[(lq * 4 + 3) * 129 + d] = v.w;
            }
            __syncthreads();
            {   // row norms, 8 threads/row
                int row = tid >> 3, q = tid & 7;
                float s = 0.f;
                #pragma unroll
                for (int j = 0; j < 16; ++j) { float t = xt[row * 129 + q * 16 + j]; s += t * t; }
                s += __shfl_down(s, 1); s += __shfl_down(s, 2); s += __shfl_down(s, 4);
                if (q == 0) {
                    float inv = 1.f / fmaxf(sqrtf(s), EPSF);
                    invl[row] = inv;
                    invn[n0 + h * 64 + row] = inv;
                }
            }
            __syncthreads();
            if (rs == h) {
                #pragma unroll
                for (int rt = 0; rt < 4; ++rt) {
                    int rl = rt * 16 + m16;          // A layout: m = lane&15
                    float inv = invl[rl];
                    #pragma unroll
                    for (int kd = 0; kd < 4; ++kd) {
                        int dof = kd * 32 + quad * 8;   // k = quad*8 + j
                        short8 hhv, llv;
                        #pragma unroll
                        for (int j = 0; j < 8; ++j) {
                            float xn = xt[rl * 129 + dof + j] * inv;
                            unsigned short hb = f2bf(xn);
                            hhv[j] = (short)hb;
                            llv[j] = (short)f2bf(xn - bf2f(hb));
                        }
                        ah[rt][kd] = hhv; al[rt][kd] = llv;
                    }
                }
            }
        }
        __syncthreads();

        // ---- K loop: 128 tiles, barrier-free ----
        const f32x4 fz = {0.f, 0.f, 0.f, 0.f};
        float Bb[16], Ss[16];
        #pragma unroll
        for (int i = 0; i < 16; ++i) { Bb[i] = -3.0e38f; Ss[i] = -3.0e38f; }
        unsigned kc8 = (unsigned)cs;     // packed tag = code>>4 = t*2+cs

        const char* pb = blob + (size_t)cs * 8192 + (size_t)lane * 16;

        auto tileStep = [&](const short8* Bf) {
            f32x4 acc[4];
            __builtin_amdgcn_s_setprio(1);
            #pragma unroll
            for (int kd = 0; kd < 4; ++kd) {
                short8 bh = Bf[kd * 2];
                short8 bl = Bf[kd * 2 + 1];
                #pragma unroll
                for (int rt = 0; rt < 4; ++rt)
                    acc[rt] = __builtin_amdgcn_mfma_f32_16x16x32_bf16(
                        ah[rt][kd], bh, (kd == 0) ? fz : acc[rt], 0, 0, 0);
                #pragma unroll
                for (int rt = 0; rt < 4; ++rt)
                    acc[rt] = __builtin_amdgcn_mfma_f32_16x16x32_bf16(
                        ah[rt][kd], bl, acc[rt], 0, 0, 0);
                #pragma unroll
                for (int rt = 0; rt < 4; ++rt)
                    acc[rt] = __builtin_amdgcn_mfma_f32_16x16x32_bf16(
                        al[rt][kd], bh, acc[rt], 0, 0, 0);
            }
            __builtin_amdgcn_s_setprio(0);
            // fold: Ss <= Bb invariant -> med3(Bb, p, Ss) exact second-best.
            #pragma unroll
            for (int rt = 0; rt < 4; ++rt)
                #pragma unroll
                for (int rg = 0; rg < 4; ++rg) {
                    int s = rt * 4 + rg;
                    float p = __uint_as_float(
                        (__float_as_uint(acc[rt][rg]) & 0xFFFFFF00u) | kc8);
                    Ss[s] = __builtin_amdgcn_fmed3f(Bb[s], p, Ss[s]);
                    Bb[s] = fmaxf(Bb[s], p);
                }
            kc8 += 2;
        };

        short8 bA[8], bB[8];
        #pragma unroll
        for (int f = 0; f < 8; ++f) bA[f] = *(const short8*)(pb + f * 1024);

        for (int tt = 0; tt < 64; ++tt) {
            {   // even tile t = 2*tt: prefetch t+1 into bB, compute bA
                const int t = 2 * tt;
                const char* p = pb + (size_t)(t + 1) * 16384;
                #pragma unroll
                for (int f = 0; f < 8; ++f) bB[f] = *(const short8*)(p + f * 1024);
                tileStep(bA);
            }
            {   // odd tile: prefetch t+1 into bA (clamp last), compute bB
                const int t = 2 * tt + 1;
                const size_t tn = (t < 127) ? (size_t)(t + 1) : (size_t)t;
                const char* p = pb + tn * 16384;
                #pragma unroll
                for (int f = 0; f < 8; ++f) bA[f] = *(const short8*)(p + f * 1024);
                tileStep(bB);
            }
        }

        // ---- epilogue: merge 16 m16-lanes per slot ----
        float mv1[16], mv2[16]; int mk1[16];
        #pragma unroll
        for (int s = 0; s < 16; ++s) {
            float v1 = Bb[s], v2 = Ss[s];
            int k1 = (int)(((__float_as_uint(v1) & 0xFFu) << 4) | (unsigned)m16);
            #pragma unroll
            for (int off = 1; off < 16; off <<= 1) {
                float ov1 = __shfl_xor(v1, off);
                float ov2 = __shfl_xor(v2, off);
                int   ok1 = __shfl_xor(k1, off);
                bool gt = ov1 > v1, eq = ov1 == v1;
                v2 = gt ? fmaxf(ov2, v1) : fmaxf(v2, ov1);
                v1 = gt ? ov1 : v1;
                k1 = gt ? ok1 : (eq ? min(k1, ok1) : k1);
            }
            mv1[s] = v1; mv2[s] = v2; mk1[s] = k1;
        }
        float* Ev = (float*)smem;                // 2048 B
        float* Sv = (float*)(smem + 2048);
        int*   Kv = (int*)(smem + 4096);
        float* bsum = (float*)(smem + 6144);
        int*   sidx = (int*)(smem + 8192);       // [256] final code per row
        __syncthreads();
        if (tid == 0) *bsum = 0.f;
        if (m16 == 0) {
            #pragma unroll
            for (int s = 0; s < 16; ++s) {
                int rt = s >> 2, rg = s & 3;
                int row = rs * 64 + rt * 16 + quad * 4 + rg;   // C row = quad*4+reg
                Ev[row * 2 + cs] = mv1[s];
                Sv[row * 2 + cs] = mv2[s];
                Kv[row * 2 + cs] = mk1[s];
            }
        }
        __syncthreads();
        if (tid < 256) {
            float v1 = Ev[tid * 2], v2 = Sv[tid * 2];
            int   k1 = Kv[tid * 2];
            float ov1 = Ev[tid * 2 + 1], ov2 = Sv[tid * 2 + 1];
            int   ok1 = Kv[tid * 2 + 1];
            bool gt = ov1 > v1, eq = ov1 == v1;
            v2 = gt ? fmaxf(ov2, v1) : fmaxf(v2, ov1);
            v1 = gt ? ov1 : v1;
            k1 = gt ? ok1 : (eq ? min(k1, ok1) : k1);
            sidx[tid] = k1;
            atomicAdd(bsum, v1);
            if (v1 - v2 < TAU) {
                int pos = atomicAdd(rcnt, 1);
                if (pos < RCAP) rlist[pos] = n0 + tid;
            }
        }
        __syncthreads();
        if (tid == 0) atomicAdd(lacc, *bsum);

        // ---- fused output write via LDS transpose: 4 chunks of 64 rows.
        int myk[4];
        #pragma unroll
        for (int c = 0; c < 4; ++c) myk[c] = sidx[c * 64 + (tid >> 3)];
        float* tb = (float*)smem;                // [64][130] = 33280 B
        float* ob = out + (size_t)bI * Dc * Lc + l0;
        #pragma unroll 1
        for (int c = 0; c < 4; ++c) {
            __syncthreads();                     // prior chunk reads / sidx done
            {
                const float4* src = (const float4*)(cbn + (size_t)myk[c] * Dc + (tid & 7) * 16);
                float4 v0 = src[0], v1 = src[1], v2 = src[2], v3 = src[3];
                float* dst = tb + (tid >> 3) * 130 + (tid & 7) * 16;
                *(float4*)(dst + 0)  = v0;
                *(float4*)(dst + 4)  = v1;
                *(float4*)(dst + 8)  = v2;
                *(float4*)(dst + 12) = v3;
            }
            __syncthreads();
            {
                int l = tid & 63, d0 = tid >> 6;     // wave = fixed d, l 0..63
                #pragma unroll
                for (int dd = 0; dd < 16; ++dd) {
                    int d = d0 * 16 + dd;
                    ob[(size_t)d * Lc + c * 64 + l] = tb[l * 130 + d];
                }
            }
        }
    }
    __threadfence();
    grid.sync();

    // ================= Phase 3: coalesced repair (r14 body) =============
    {
        float* xs = (float*)smem;                              // [128]
        unsigned long long* red = (unsigned long long*)(smem + 512); // [8]
        int* fk = (int*)(smem + 576);
        int cnt = *rcnt; if (cnt > RCAP) cnt = RCAP;
        const int half = lane >> 5;        // 0: even code, 1: odd code
        const int l32  = lane & 31;
        for (int e = blockIdx.x; e < cnt; e += gridDim.x) {
            int n = rlist[e]; int b = n >> 12; int l = n & (Lc - 1);
            __syncthreads();
            if (tid < 128)
                xs[tid] = x[(size_t)b * Dc * Lc + (size_t)tid * Lc + l] * invn[n];
            __syncthreads();
            const float4 xv = ((const float4*)xs)[l32];   // lane's 4 dims
            float best = -3.0e38f; int bk = 0;
            // wave w owns codes [w*512, w*512+512); pair (k,k+1) per iter
            #pragma unroll 4
            for (int i = 0; i < 256; ++i) {
                int k = w * 512 + i * 2 + half;
                float4 cv = ((const float4*)(cbn + (size_t)k * Dc))[l32];
                float s = cv.x * xv.x;
                s = fmaf(cv.y, xv.y, s);
                s = fmaf(cv.z, xv.z, s);
                s = fmaf(cv.w, xv.w, s);
                #pragma unroll
                for (int off = 1; off < 32; off <<= 1)
                    s += __shfl_xor(s, off);     // tree sum per half-wave
                if (s > best) { best = s; bk = k; }   // ascending k per half
            }
            unsigned kb = __float_as_uint(best);
            kb = (kb & 0x80000000u) ? ~kb : (kb | 0x80000000u);
            unsigned long long pk =
                ((unsigned long long)kb << 32) | (unsigned)(0xFFFFFFFFu - (unsigned)bk);
            #pragma unroll
            for (int off = 1; off < 64; off <<= 1) {
                unsigned long long o = __shfl_xor(pk, off);
                pk = (o > pk) ? o : pk;
            }
            if (lane == 0) red[w] = pk;
            __syncthreads();
            if (tid == 0) {
                unsigned long long m = red[0];
                #pragma unroll
                for (int i = 1; i < 8; ++i) if (red[i] > m) m = red[i];
                *fk = (int)(0xFFFFFFFFu - (unsigned)(m & 0xFFFFFFFFull));
            }
            __syncthreads();
            if (tid < 128)
                out[(size_t)b * Dc * Lc + (size_t)tid * Lc + l] =
                    cbn[(size_t)(*fk) * Dc + tid];
        }
    }
    __threadfence();
    grid.sync();

    // ================= loss finalize =================
    if (blockIdx.x == 0 && tid == 0)
        out[(size_t)Bc * Dc * Lc] = 2.0f - 2.0f * (*lacc) / (float)Nc;
}

// ---------------------------------------------------------------------------
extern "C" void kernel_launch(void* const* d_in, const int* in_sizes, int n_in,
                              void* d_out, int out_size, void* d_ws, size_t ws_size,
                              hipStream_t stream) {
    const float* x   = (const float*)d_in[0];   // [16][128][4096] fp32
    const float* emb = (const float*)d_in[1];   // [4096][128] fp32
    float* out = (float*)d_out;

    char* ws = (char*)d_ws;
    float* cbn  = (float*)ws;                                  // 2 MB
    char*  blob = ws + (2u << 20);                             // 2 MB
    float* invn = (float*)(ws + (4u << 20));                   // 256 KB
    char*  b5   = ws + (4u << 20) + (512u << 10);
    float* lacc = (float*)b5;
    int*   rcnt = (int*)(b5 + 64);
    int*   rlist= (int*)(b5 + 1024);                           // 128 KB

    void* kargs[] = {
        (void*)&emb, (void*)&x, (void*)&cbn, (void*)&blob, (void*)&invn,
        (void*)&out, (void*)&lacc, (void*)&rcnt, (void*)&rlist
    };
    hipLaunchCooperativeKernel((const void*)k_fused, dim3(Nc / 256), dim3(512),
                               kargs, 0, stream);
}

// Round 16
// 325.834 us; speedup vs baseline: 1.6164x; 1.6164x over previous
//
#include <hip/hip_runtime.h>
#include <cstddef>

#define EPSF 1e-12f

constexpr int Bc = 16, Dc = 128, Lc = 4096, Kc = 4096;
constexpr int Nc = Bc * Lc;     // 65536
constexpr float TAU = 1e-4f;    // 2x split-bf16 err (~4e-5) + 8-bit pack err (~6e-5)
constexpr int RCAP = 32768;

typedef __attribute__((ext_vector_type(8))) short short8;
typedef __attribute__((ext_vector_type(4))) float f32x4;

__device__ __forceinline__ unsigned short f2bf(float f) {
    unsigned u = __float_as_uint(f);
    return (unsigned short)((u + 0x7fffu + ((u >> 16) & 1u)) >> 16);
}
__device__ __forceinline__ float bf2f(unsigned short u) {
    return __uint_as_float(((unsigned)u) << 16);
}

// ---------------------------------------------------------------------------
// Fused codebook prep: normalize -> cbn (f32) AND pack MFMA-operand blob.
// Blob layout: group g (16 codes) -> 8 frags (kd 0..3 x {hi,lo}) of 1024B;
// within a frag, 16B slot l = q*16 + (k&15) holds bf16 of dims (kd*4+q)*8..+7
// of code k. Zero-inits loss / repair counter / done (graph-replay safe).
// ---------------------------------------------------------------------------
__global__ void k_prep(const float* __restrict__ emb, float* __restrict__ cbn,
                       char* __restrict__ blob, float* __restrict__ lacc,
                       int* __restrict__ rcnt, int* __restrict__ done) {
    __shared__ float cls[4][128];
    const int tid  = threadIdx.x;
    const int w    = tid >> 6;
    const int lane = tid & 63;
    const int k    = (blockIdx.x << 2) + w;

    float2 v = ((const float2*)(emb + (size_t)k * Dc))[lane];
    float s = v.x * v.x + v.y * v.y;
    #pragma unroll
    for (int off = 32; off > 0; off >>= 1) s += __shfl_down(s, off);
    s = __shfl(s, 0);
    float inv = 1.f / fmaxf(sqrtf(s), EPSF);
    v.x *= inv; v.y *= inv;
    ((float2*)(cbn + (size_t)k * Dc))[lane] = v;
    cls[w][lane * 2]     = v.x;
    cls[w][lane * 2 + 1] = v.y;
    if (blockIdx.x == 0 && tid == 0) { *lacc = 0.f; *rcnt = 0; *done = 0; }
    __syncthreads();

    if (tid < 64) {           // 4 codes x 16 chunks
        int kl = tid >> 4, c = tid & 15;
        int kk = (blockIdx.x << 2) + kl;
        int kd = c >> 2, q = c & 3;
        short8 hh, ll;
        #pragma unroll
        for (int j = 0; j < 8; ++j) {
            float f = cls[kl][c * 8 + j];
            unsigned short hb = f2bf(f);
            hh[j] = (short)hb;
            ll[j] = (short)f2bf(f - bf2f(hb));
        }
        size_t base = (size_t)(kk >> 4) * 8192 + (size_t)(q * 16 + (kk & 15)) * 16;
        *(short8*)(blob + base + (kd * 2 + 0) * 1024) = hh;
        *(short8*)(blob + base + (kd * 2 + 1) * 1024) = ll;
    }
}

// ---------------------------------------------------------------------------
// MFMA argmax — exact round-9 structure (best measured: 177.8 us, MfmaUtil
// 53.5%, ~95% of the 16x16 MFMA issue ceiling at 2 waves/SIMD). Block =
// 512 thr / 8 waves = (4 rowsets x 2 codesets), 256 rows/block, grid 256.
// Barrier-free K-loop, blob L2-resident, global->VGPR ping-pong, med3
// second-best fold, setprio around the MFMA cluster.
// NOTE (r7/r10): raising min-waves caps VGPR far below the ~250-reg demand
// -> multi-GB spill. 2 waves/SIMD is the occupancy ceiling for this shape.
// NOTE (r15): cooperative fusion of the 3 kernels adds ~260 us of stall
// (grid.sync + codegen perturbation) — separate dispatches are faster.
// Tail: LDS-transposed gather-write.
// ---------------------------------------------------------------------------
__global__ __launch_bounds__(512, 2)
void k_argmax(const float* __restrict__ x, const char* __restrict__ blob,
              const float* __restrict__ cbn, float* __restrict__ invn,
              float* __restrict__ out, float* __restrict__ lossacc,
              int* __restrict__ rcnt, int* __restrict__ rlist) {
    __shared__ __align__(16) char smem[33280];
    float* xt   = (float*)smem;              // [64][129] (preamble overlay)
    float* invl = (float*)(smem + 33024);    // [64]

    const int tid  = threadIdx.x;
    const int w    = tid >> 6;
    const int lane = tid & 63;
    const int m16  = lane & 15;
    const int quad = lane >> 4;
    const int rs   = w >> 1;      // rowset 0..3 (64 rows each)
    const int cs   = w & 1;       // codeset 0/1 (16 codes per tile)
    const int n0   = blockIdx.x * 256;
    const int bI   = n0 >> 12;
    const int l0   = n0 & (Lc - 1);
    const float* xb = x + (size_t)bI * Dc * Lc;

    // ---- preamble: 4 halves of 64 rows: transpose, normalize, build A frags
    short8 ah[4][4], al[4][4];
    for (int h = 0; h < 4; ++h) {
        __syncthreads();
        #pragma unroll
        for (int j = 0; j < 4; ++j) {
            int fl = tid + j * 512;              // 0..2047
            int d = fl >> 4, lq = fl & 15;
            float4 v = *(const float4*)(xb + (size_t)d * Lc + l0 + h * 64 + lq * 4);
            xt[(lq * 4 + 0) * 129 + d] = v.x;
            xt[(lq * 4 + 1) * 129 + d] = v.y;
            xt[(lq * 4 + 2) * 129 + d] = v.z;
            xt[(lq * 4 + 3) * 129 + d] = v.w;
        }
        __syncthreads();
        {   // row norms, 8 threads/row
            int row = tid >> 3, q = tid & 7;
            float s = 0.f;
            #pragma unroll
            for (int j = 0; j < 16; ++j) { float t = xt[row * 129 + q * 16 + j]; s += t * t; }
            s += __shfl_down(s, 1); s += __shfl_down(s, 2); s += __shfl_down(s, 4);
            if (q == 0) {
                float inv = 1.f / fmaxf(sqrtf(s), EPSF);
                invl[row] = inv;
                invn[n0 + h * 64 + row] = inv;
            }
        }
        __syncthreads();
        if (rs == h) {   // both cs-waves of this rowset build the frags
            #pragma unroll
            for (int rt = 0; rt < 4; ++rt) {
                int rl = rt * 16 + m16;          // A layout: m = lane&15
                float inv = invl[rl];
                #pragma unroll
                for (int kd = 0; kd < 4; ++kd) {
                    int dof = kd * 32 + quad * 8;   // k = quad*8 + j
                    short8 hhv, llv;
                    #pragma unroll
                    for (int j = 0; j < 8; ++j) {
                        float xn = xt[rl * 129 + dof + j] * inv;
                        unsigned short hb = f2bf(xn);
                        hhv[j] = (short)hb;
                        llv[j] = (short)f2bf(xn - bf2f(hb));
                    }
                    ah[rt][kd] = hhv; al[rt][kd] = llv;
                }
            }
        }
    }
    __syncthreads();

    // ---- K loop: 128 tiles of 32 codes (16 per codeset), barrier-free ----
    const f32x4 fz = {0.f, 0.f, 0.f, 0.f};
    float Bb[16], Ss[16];
    #pragma unroll
    for (int i = 0; i < 16; ++i) { Bb[i] = -3.0e38f; Ss[i] = -3.0e38f; }
    unsigned kc8 = (unsigned)cs;     // packed tag = code>>4 = t*2+cs

    const char* pb = blob + (size_t)cs * 8192 + (size_t)lane * 16;

    auto tileStep = [&](const short8* Bf) {
        f32x4 acc[4];
        __builtin_amdgcn_s_setprio(1);
        #pragma unroll
        for (int kd = 0; kd < 4; ++kd) {
            short8 bh = Bf[kd * 2];
            short8 bl = Bf[kd * 2 + 1];
            #pragma unroll
            for (int rt = 0; rt < 4; ++rt)
                acc[rt] = __builtin_amdgcn_mfma_f32_16x16x32_bf16(
                    ah[rt][kd], bh, (kd == 0) ? fz : acc[rt], 0, 0, 0);
            #pragma unroll
            for (int rt = 0; rt < 4; ++rt)
                acc[rt] = __builtin_amdgcn_mfma_f32_16x16x32_bf16(
                    ah[rt][kd], bl, acc[rt], 0, 0, 0);
            #pragma unroll
            for (int rt = 0; rt < 4; ++rt)
                acc[rt] = __builtin_amdgcn_mfma_f32_16x16x32_bf16(
                    al[rt][kd], bh, acc[rt], 0, 0, 0);
        }
        __builtin_amdgcn_s_setprio(0);
        // fold: Ss <= Bb invariant -> med3(Bb, p, Ss) is exact second-best.
        #pragma unroll
        for (int rt = 0; rt < 4; ++rt)
            #pragma unroll
            for (int rg = 0; rg < 4; ++rg) {
                int s = rt * 4 + rg;
                float p = __uint_as_float(
                    (__float_as_uint(acc[rt][rg]) & 0xFFFFFF00u) | kc8);
                Ss[s] = __builtin_amdgcn_fmed3f(Bb[s], p, Ss[s]);
                Bb[s] = fmaxf(Bb[s], p);
            }
        kc8 += 2;
    };

    short8 bA[8], bB[8];
    #pragma unroll
    for (int f = 0; f < 8; ++f) bA[f] = *(const short8*)(pb + f * 1024);

    for (int tt = 0; tt < 64; ++tt) {
        {   // even tile t = 2*tt: prefetch t+1 into bB, compute bA
            const int t = 2 * tt;
            const char* p = pb + (size_t)(t + 1) * 16384;
            #pragma unroll
            for (int f = 0; f < 8; ++f) bB[f] = *(const short8*)(p + f * 1024);
            tileStep(bA);
        }
        {   // odd tile t = 2*tt+1: prefetch t+1 into bA (clamp last), compute bB
            const int t = 2 * tt + 1;
            const size_t tn = (t < 127) ? (size_t)(t + 1) : (size_t)t;
            const char* p = pb + tn * 16384;
            #pragma unroll
            for (int f = 0; f < 8; ++f) bA[f] = *(const short8*)(p + f * 1024);
            tileStep(bB);
        }
    }

    // ---- epilogue: merge 16 m16-lanes per slot ----
    float mv1[16], mv2[16]; int mk1[16];
    #pragma unroll
    for (int s = 0; s < 16; ++s) {
        float v1 = Bb[s], v2 = Ss[s];
        int k1 = (int)(((__float_as_uint(v1) & 0xFFu) << 4) | (unsigned)m16);
        #pragma unroll
        for (int off = 1; off < 16; off <<= 1) {
            float ov1 = __shfl_xor(v1, off);
            float ov2 = __shfl_xor(v2, off);
            int   ok1 = __shfl_xor(k1, off);
            bool gt = ov1 > v1, eq = ov1 == v1;
            v2 = gt ? fmaxf(ov2, v1) : fmaxf(v2, ov1);
            v1 = gt ? ov1 : v1;
            k1 = gt ? ok1 : (eq ? min(k1, ok1) : k1);
        }
        mv1[s] = v1; mv2[s] = v2; mk1[s] = k1;
    }
    // cross-codeset merge via LDS: [256 rows][2 cs]
    float* Ev = (float*)smem;                // 2048 B
    float* Sv = (float*)(smem + 2048);
    int*   Kv = (int*)(smem + 4096);
    float* bsum = (float*)(smem + 6144);
    int*   sidx = (int*)(smem + 8192);       // [256] final code per row
    __syncthreads();
    if (tid == 0) *bsum = 0.f;
    if (m16 == 0) {
        #pragma unroll
        for (int s = 0; s < 16; ++s) {
            int rt = s >> 2, rg = s & 3;
            int row = rs * 64 + rt * 16 + quad * 4 + rg;   // C row = quad*4+reg
            Ev[row * 2 + cs] = mv1[s];
            Sv[row * 2 + cs] = mv2[s];
            Kv[row * 2 + cs] = mk1[s];
        }
    }
    __syncthreads();
    if (tid < 256) {
        float v1 = Ev[tid * 2], v2 = Sv[tid * 2];
        int   k1 = Kv[tid * 2];
        float ov1 = Ev[tid * 2 + 1], ov2 = Sv[tid * 2 + 1];
        int   ok1 = Kv[tid * 2 + 1];
        bool gt = ov1 > v1, eq = ov1 == v1;
        v2 = gt ? fmaxf(ov2, v1) : fmaxf(v2, ov1);
        v1 = gt ? ov1 : v1;
        k1 = gt ? ok1 : (eq ? min(k1, ok1) : k1);
        sidx[tid] = k1;
        atomicAdd(bsum, v1);
        if (v1 - v2 < TAU) {
            int pos = atomicAdd(rcnt, 1);
            if (pos < RCAP) rlist[pos] = n0 + tid;
        }
    }
    __syncthreads();
    if (tid == 0) atomicAdd(lossacc, *bsum);

    // ---- fused output write via LDS transpose: 4 chunks of 64 rows.
    int myk[4];
    #pragma unroll
    for (int c = 0; c < 4; ++c) myk[c] = sidx[c * 64 + (tid >> 3)];
    float* tb = (float*)smem;                // [64][130] = 33280 B
    float* ob = out + (size_t)bI * Dc * Lc + l0;
    #pragma unroll 1
    for (int c = 0; c < 4; ++c) {
        __syncthreads();                     // prior chunk reads / sidx done
        {
            const float4* src = (const float4*)(cbn + (size_t)myk[c] * Dc + (tid & 7) * 16);
            float4 v0 = src[0], v1 = src[1], v2 = src[2], v3 = src[3];
            float* dst = tb + (tid >> 3) * 130 + (tid & 7) * 16;
            *(float4*)(dst + 0)  = v0;
            *(float4*)(dst + 4)  = v1;
            *(float4*)(dst + 8)  = v2;
            *(float4*)(dst + 12) = v3;
        }
        __syncthreads();
        {
            int l = tid & 63, d0 = tid >> 6;     // wave = fixed d, l 0..63
            #pragma unroll
            for (int dd = 0; dd < 16; ++dd) {
                int d = d0 * 16 + dd;
                ob[(size_t)d * Lc + c * 64 + l] = tb[l * 130 + d];
            }
        }
    }
}

// ---------------------------------------------------------------------------
// Exact fp32 re-argmax, COALESCED: wave-per-code-pair. Lanes 0-31 hold code
// k's 128 floats (float4/lane), lanes 32-63 code k+1 -> every code load is
// one coalesced 1KB wave transaction (vs 64 scattered lines in all prior
// variants: the r5-r13 repairs were request-rate bound, ~140-370 us at
// VALUBusy ~1.5%). Dot = 4-dim lane chain + 5-step shfl_xor tree per half;
// per-half running (best,bk); final packed-key (v1|~k) max-reduce across
// lanes + waves -> exact max-v1 / min-k, partition-order independent.
// Rewrites out row; last block (done counter) writes the scalar loss.
// ---------------------------------------------------------------------------
__global__ __launch_bounds__(512)
void k_repair(const float* __restrict__ x, const float* __restrict__ invn,
              const float* __restrict__ cbn, float* __restrict__ out,
              const int* __restrict__ rcnt, const int* __restrict__ rlist,
              const float* __restrict__ lacc, int* __restrict__ done) {
    __shared__ __align__(16) float xs[128];
    __shared__ unsigned long long red[8];
    __shared__ int fk;
    int cnt = *rcnt; if (cnt > RCAP) cnt = RCAP;
    const int tid  = threadIdx.x;
    const int w    = tid >> 6;
    const int lane = tid & 63;
    const int half = lane >> 5;        // 0: even code, 1: odd code
    const int l32  = lane & 31;
    for (int e = blockIdx.x; e < cnt; e += gridDim.x) {
        int n = rlist[e]; int b = n >> 12; int l = n & (Lc - 1);
        __syncthreads();
        if (tid < 128)
            xs[tid] = x[(size_t)b * Dc * Lc + (size_t)tid * Lc + l] * invn[n];
        __syncthreads();
        const float4 xv = ((const float4*)xs)[l32];   // lane's 4 dims (fixed)
        float best = -3.0e38f; int bk = 0;
        // wave w owns codes [w*512, w*512+512); pair (k, k+1) per iteration
        #pragma unroll 4
        for (int i = 0; i < 256; ++i) {
            int k = w * 512 + i * 2 + half;
            float4 cv = ((const float4*)(cbn + (size_t)k * Dc))[l32];
            float s = cv.x * xv.x;
            s = fmaf(cv.y, xv.y, s);
            s = fmaf(cv.z, xv.z, s);
            s = fmaf(cv.w, xv.w, s);
            #pragma unroll
            for (int off = 1; off < 32; off <<= 1)
                s += __shfl_xor(s, off);     // tree sum within each half-wave
            if (s > best) { best = s; bk = k; }   // ascending k per half
        }
        // packed key: max v1, tie -> min k (order-independent)
        unsigned kb = __float_as_uint(best);
        kb = (kb & 0x80000000u) ? ~kb : (kb | 0x80000000u);
        unsigned long long pk =
            ((unsigned long long)kb << 32) | (unsigned)(0xFFFFFFFFu - (unsigned)bk);
        #pragma unroll
        for (int off = 1; off < 64; off <<= 1) {
            unsigned long long o = __shfl_xor(pk, off);
            pk = (o > pk) ? o : pk;
        }
        if (lane == 0) red[w] = pk;
        __syncthreads();
        if (tid == 0) {
            unsigned long long m = red[0];
            #pragma unroll
            for (int i = 1; i < 8; ++i) if (red[i] > m) m = red[i];
            fk = (int)(0xFFFFFFFFu - (unsigned)(m & 0xFFFFFFFFull));
        }
        __syncthreads();
        if (tid < 128)       // rewrite output row with exact code
            out[(size_t)b * Dc * Lc + (size_t)tid * Lc + l] = cbn[(size_t)fk * Dc + tid];
    }
    // ---- fused loss finalize: last block writes the scalar
    __syncthreads();
    if (tid == 0) {
        int old = atomicAdd(done, 1);
        if (old == (int)gridDim.x - 1)
            out[(size_t)Bc * Dc * Lc] = 2.0f - 2.0f * (*lacc) / (float)Nc;
    }
}

// ---------------------------------------------------------------------------
extern "C" void kernel_launch(void* const* d_in, const int* in_sizes, int n_in,
                              void* d_out, int out_size, void* d_ws, size_t ws_size,
                              hipStream_t stream) {
    const float* x   = (const float*)d_in[0];   // [16][128][4096] fp32
    const float* emb = (const float*)d_in[1];   // [4096][128] fp32
    float* out = (float*)d_out;

    char* ws = (char*)d_ws;
    float* cbn  = (float*)ws;                                  // 2 MB
    char*  blob = ws + (2u << 20);                             // 2 MB
    float* invn = (float*)(ws + (4u << 20));                   // 256 KB
    char*  b5   = ws + (4u << 20) + (512u << 10);
    float* lacc = (float*)b5;
    int*   rcnt = (int*)(b5 + 64);
    int*   done = (int*)(b5 + 128);
    int*   rlist= (int*)(b5 + 1024);                           // 128 KB

    k_prep  <<<Kc / 4,   256, 0, stream>>>(emb, cbn, blob, lacc, rcnt, done);
    k_argmax<<<Nc / 256, 512, 0, stream>>>(x, blob, cbn, invn, out, lacc, rcnt, rlist);
    k_repair<<<2048,     512, 0, stream>>>(x, invn, cbn, out, rcnt, rlist, lacc, done);
}